// Round 7
// baseline (178.146 us; speedup 1.0000x reference)
//
#include <hip/hip_runtime.h>

#define NR 24
#define NBATCH 2
#define NFEAT 2
#define NX 256
#define NY 256
#define NZ 16
#define SLOTS 27          // bins -1..25 unwrapped (no mod-24 in hot loop)
#define ROWS_PER_BLK 2
#define NBLK_PER_BF 256   // 128 row-pairs x 2 col-halves
#define NPART (NR * NZ)   // 384 outputs per bf
#define NOUT (NBATCH * NFEAT * NPART)
#define NBLOCKS (NBATCH * NFEAT * NBLK_PER_BF)          // 1024 = 4/CU, all co-resident
#define FLAGS_OFF ((size_t)NOUT * NBLK_PER_BF)          // flags after 1.5 MiB partials
#define MAGIC 0x5F3C9A17u

// Single-launch producer-consumer (round 7).
// Budget (rounds 0-6): fill 42.7 (fixed) + ~8 us per graph node + partial ~13
// + reduce ~3. R5 proved grid.sync costs ~70 us -> fuse WITHOUT grid sync:
// all 1024 blocks are co-resident (27.6 KiB LDS -> 5 blocks/CU capacity,
// grid needs 4/CU), so flag-spin cannot deadlock. Cross-XCD visibility per
// G16/m20: partials + flags use agent-scope (sc1) atomics completing at the
// LLC, bypassing the non-coherent per-XCD L2s. Producer: stores -> per-thread
// __threadfence -> __syncthreads -> one RELEASE flag store. Reducers (blocks
// 0..383) ACQUIRE-spin on their bf's 256 flags, then relaxed-agent data loads.
// Flags live in poisoned ws (reset every iteration by the harness fill);
// replay without re-poison is also safe: partials are deterministic, so
// stale-MAGIC early reads return identical values.
//
// Producer phase = round-4 kernel verbatim: transposed LDS red[slot][tid]
// (bank = tid%32, conflict-free vs data-dependent slot; 2-way l/l+32 free).
__global__ __launch_bounds__(256) void grx_fused(
    const float* __restrict__ x,
    const float* __restrict__ com_real,
    const float* __restrict__ com_imag,
    float* __restrict__ ws,
    float* __restrict__ out)
{
    __shared__ float red[SLOTS][256];   // 27.6 KiB

    const int tid  = threadIdx.x;
    const int z    = tid & 15;
    const int c0   = tid >> 4;
    const int half = blockIdx.x & 1;
    const int rp   = (blockIdx.x >> 1) & 127;
    const int bf   = blockIdx.x >> 8;          // 0..3

    // cooperative vectorized zero: 1728 float4, 7 b128 stores/thread
    float4* r4 = (float4*)&red[0][0];
    #pragma unroll
    for (int i = 0; i < 7; ++i) {
        const int idx = tid + i * 256;
        if (idx < (SLOTS * 256 / 4)) r4[idx] = make_float4(0.f, 0.f, 0.f, 0.f);
    }
    __syncthreads();

    const float comr = com_real[bf * NZ + z];
    const float comi = com_imag[bf * NZ + z];

    // atan poly coefficients pre-scaled by 12/pi (result directly in bin units)
    const float A4 = 0.0795845f;
    const float A3 = -0.3251843f;
    const float A2 = 0.6880875f;
    const float A1 = -1.2616510f;
    const float A0 = 3.8192070f;
    const float C_E = -3.4269908169872414f;    // -50*(pi/12)^2

    const int col0 = c0 + (half << 7);
    float* mycol = &red[0][tid];               // column owned by this thread

    #pragma unroll
    for (int rr_ = 0; rr_ < ROWS_PER_BLK; ++rr_) {
        const int row   = rp * ROWS_PER_BLK + rr_;
        const float dyv = (float)row - comi;
        const float ady = fabsf(dyv);
        const float* xq = x + ((size_t)(bf * NX + row)) * (NY * NZ) + (col0 * NZ + z);
        float dxv = (float)col0 - comr;          // col start; += 16 per iter

        #pragma unroll
        for (int kk = 0; kk < 8; ++kk) {
            const float xv = xq[kk * 256];       // 64 consecutive floats per wave

            // ---- custom atan2 in bin units (|err| ~1e-5 rad equiv) ----
            const float adx = fabsf(dxv);
            const float mn  = fminf(adx, ady);
            const float mx  = fmaxf(adx, ady);
            const float t   = mn * __builtin_amdgcn_rcpf(fmaxf(mx, 1e-30f));
            const float r2  = t * t;
            float p = fmaf(r2, A4, A3);
            p = fmaf(r2, p, A2);
            p = fmaf(r2, p, A1);
            p = fmaf(r2, p, A0);
            float psi = t * p;                   // [0, 6]
            if (ady > adx)  psi = 6.0f - psi;
            if (dxv < 0.0f) psi = 12.0f - psi;
            psi = copysignf(psi, dyv);           // (-12, 12]
            dxv += 16.0f;

            // ---- 3-neighbor circular binning, unwrapped slots ----
            const float nf  = rintf(psi);
            const float f   = psi - nf;          // [-0.5, 0.5]
            const int base  = (int)nf + 12;      // [0, 24] -> slots base..base+2

            const float fm = f + 1.0f;
            const float fp = f - 1.0f;
            const float wm = __expf(C_E * fm * fm) * xv;  // -> slot base
            const float w0 = __expf(C_E * f  * f ) * xv;  // -> slot base+1
            const float wp = __expf(C_E * fp * fp) * xv;  // -> slot base+2

            // conflict-free 3-tap RMW down one bank column
            float* pb = mycol + (base << 8);     // &red[base][tid]
            float a0 = pb[0];
            float a1 = pb[256];
            float a2 = pb[512];
            a0 += wm; a1 += w0; a2 += wp;
            pb[0]   = a0;
            pb[256] = a1;
            pb[512] = a2;
        }
    }

    __syncthreads();

    // Tail: reduce 16 col-phases per (r,z); fold wrap slots; store partials
    // with agent-scope relaxed stores (complete at LLC, cross-XCD visible).
    const int l = blockIdx.x & (NBLK_PER_BF - 1);
    for (int o = tid; o < NPART; o += 256) {
        const int r  = o >> 4;
        const int zz = o & 15;
        float s = 0.0f;
        #pragma unroll
        for (int c = 0; c < 16; ++c) {
            float v = red[r + 1][c * 16 + zz];   // slot r+1 holds bin r
            if (r == 0)  v += red[25][c * 16 + zz];  // bin 24 == 0
            if (r == 1)  v += red[26][c * 16 + zz];  // bin 25 == 1
            if (r == 23) v += red[0][c * 16 + zz];   // bin -1 == 23
            s += v;
        }
        __hip_atomic_store(&ws[((size_t)(bf * NPART + o) * NBLK_PER_BF) + l], s,
                           __ATOMIC_RELAXED, __HIP_MEMORY_SCOPE_AGENT);
    }

    // publish: every thread drains its own stores, then one RELEASE flag
    __threadfence();
    __syncthreads();
    unsigned int* flags = (unsigned int*)(ws + FLAGS_OFF);
    if (tid == 0)
        __hip_atomic_store(&flags[blockIdx.x], MAGIC,
                           __ATOMIC_RELEASE, __HIP_MEMORY_SCOPE_AGENT);

    if (blockIdx.x >= NOUT / 4) return;

    // ---- consumer phase: blocks 0..383, one wave per output ----
    const int bfr = blockIdx.x / (NOUT / 4 / (NBATCH * NFEAT));  // /96 -> bf of outputs
    while (__hip_atomic_load(&flags[bfr * NBLK_PER_BF + tid],
                             __ATOMIC_ACQUIRE, __HIP_MEMORY_SCOPE_AGENT) != MAGIC) {}
    __syncthreads();

    const int o    = blockIdx.x * 4 + (tid >> 6);   // global output index
    const int lane = tid & 63;
    float* pbase = ws + (size_t)o * NBLK_PER_BF;
    float s = 0.0f;
    #pragma unroll
    for (int j = 0; j < 4; ++j)
        s += __hip_atomic_load(&pbase[lane + j * 64],
                               __ATOMIC_RELAXED, __HIP_MEMORY_SCOPE_AGENT);
    #pragma unroll
    for (int off = 32; off; off >>= 1) s += __shfl_down(s, off, 64);
    if (lane == 0) {
        // 2 * 1/(sigma*sqrt(2*pi))
        out[o] = sqrtf(7.9788456080286535f * s);
    }
}

extern "C" void kernel_launch(void* const* d_in, const int* in_sizes, int n_in,
                              void* d_out, int out_size, void* d_ws, size_t ws_size,
                              hipStream_t stream)
{
    const float* x  = (const float*)d_in[0];
    const float* cr = (const float*)d_in[1];
    const float* ci = (const float*)d_in[2];
    float* out = (float*)d_out;
    float* ws  = (float*)d_ws;

    grx_fused<<<dim3(NBLOCKS), dim3(256), 0, stream>>>(x, cr, ci, ws, out);
}

// Round 8
// 135.671 us; speedup vs baseline: 1.3131x; 1.3131x over previous
//
#include <hip/hip_runtime.h>

#define NR 24
#define NBATCH 2
#define NFEAT 2
#define NX 256
#define NY 256
#define NZ 16
#define SLOTS 27          // bins -1..25 unwrapped (no mod-24 in hot loop)
#define NBLK_PER_BF 256   // 128 row-pairs x 2 col-halves
#define NPART (NR * NZ)   // 384 outputs per bf
#define NOUT (NBATCH * NFEAT * NPART)
#define NBLOCKS (NBATCH * NFEAT * NBLK_PER_BF)   // 1024

// Single-launch, wait-free (round 8).
// Hard-won constants: grid.sync ~70us (R5), flag-spin handshake ~95us (R7) ->
// consumers must NEVER wait. Last-block-done instead: every block atomicAdds
// its 384 partials into __device__ accumulators (device-scope atomics, LLC-
// coherent across XCDs; R2 proved this tail ~1us and numerically fine), bumps
// a counter; the block drawing old==NBLOCKS-1 finalizes all 1536 outputs.
// Zero-init without a memset node: g_acc/g_count live in .bss (zeroed at module
// load); the last block RESETS them after finalizing -> invariant restored for
// every graph replay. ws untouched (its 42.7us poison fill is unconditional).
// Node count 3 -> 2 (~ -5.2us by the fitted overhead model).
//
// Hot loop: rows interleaved per kk step -- two independent latency chains
// (global load -> atan2 -> exp -> LDS RMW) per thread, shared fabsf(dx)/sign
// logic. The two RMWs stay in program order: DS pipe is in-order per wave, so
// base0==base1 (adjacent rows, similar angle) still accumulates correctly.
// LDS transposed red[slot][tid]: bank = tid%32, conflict-free vs data-dependent
// slot (2-way l/l+32 aliasing free, m136).

__device__ __align__(16) float g_acc[NOUT];   // .bss -> zero at load
__device__ unsigned int g_count;              // .bss -> zero at load

__global__ __launch_bounds__(256) void grx_fused(
    const float* __restrict__ x,
    const float* __restrict__ com_real,
    const float* __restrict__ com_imag,
    float* __restrict__ out)
{
    __shared__ float red[SLOTS][256];   // 27.6 KiB -> 4 blocks/CU resident

    const int tid  = threadIdx.x;
    const int z    = tid & 15;
    const int c0   = tid >> 4;
    const int half = blockIdx.x & 1;
    const int rp   = (blockIdx.x >> 1) & 127;
    const int bf   = blockIdx.x >> 8;          // 0..3

    // cooperative vectorized zero: 1728 float4, 7 b128 stores/thread
    float4* r4 = (float4*)&red[0][0];
    #pragma unroll
    for (int i = 0; i < 7; ++i) {
        const int idx = tid + i * 256;
        if (idx < (SLOTS * 256 / 4)) r4[idx] = make_float4(0.f, 0.f, 0.f, 0.f);
    }
    __syncthreads();

    const float comr = com_real[bf * NZ + z];
    const float comi = com_imag[bf * NZ + z];

    // atan poly coefficients pre-scaled by 12/pi (result directly in bin units)
    const float A4 = 0.0795845f;
    const float A3 = -0.3251843f;
    const float A2 = 0.6880875f;
    const float A1 = -1.2616510f;
    const float A0 = 3.8192070f;
    const float C_E = -3.4269908169872414f;    // -50*(pi/12)^2

    const int col0 = c0 + (half << 7);
    float* mycol = &red[0][tid];               // column owned by this thread

    const int row0   = rp * 2;
    const float dy0  = (float)row0 - comi;
    const float dy1  = dy0 + 1.0f;
    const float ady0 = fabsf(dy0);
    const float ady1 = fabsf(dy1);
    const float* xq0 = x + ((size_t)(bf * NX + row0) * (NY * NZ)) + (col0 * NZ + z);
    const float* xq1 = xq0 + NY * NZ;
    float dxv = (float)col0 - comr;            // shared by both rows; += 16/iter

    #pragma unroll
    for (int kk = 0; kk < 8; ++kk) {
        const float xv0 = xq0[kk * 256];       // 64 consecutive floats per wave
        const float xv1 = xq1[kk * 256];

        const float adx = fabsf(dxv);
        const bool  neg = (dxv < 0.0f);

        // ---- row 0: custom atan2 in bin units ----
        const float mn0 = fminf(adx, ady0);
        const float mx0 = fmaxf(adx, ady0);
        const float t0  = mn0 * __builtin_amdgcn_rcpf(fmaxf(mx0, 1e-30f));
        const float q0  = t0 * t0;
        float p0 = fmaf(q0, A4, A3);
        p0 = fmaf(q0, p0, A2);
        p0 = fmaf(q0, p0, A1);
        p0 = fmaf(q0, p0, A0);
        float psi0 = t0 * p0;
        if (ady0 > adx) psi0 = 6.0f - psi0;
        if (neg)        psi0 = 12.0f - psi0;
        psi0 = copysignf(psi0, dy0);

        // ---- row 1: custom atan2 in bin units ----
        const float mn1 = fminf(adx, ady1);
        const float mx1 = fmaxf(adx, ady1);
        const float t1  = mn1 * __builtin_amdgcn_rcpf(fmaxf(mx1, 1e-30f));
        const float q1  = t1 * t1;
        float p1 = fmaf(q1, A4, A3);
        p1 = fmaf(q1, p1, A2);
        p1 = fmaf(q1, p1, A1);
        p1 = fmaf(q1, p1, A0);
        float psi1 = t1 * p1;
        if (ady1 > adx) psi1 = 6.0f - psi1;
        if (neg)        psi1 = 12.0f - psi1;
        psi1 = copysignf(psi1, dy1);

        dxv += 16.0f;

        // ---- row 0: 3-neighbor binning + RMW ----
        {
            const float nf = rintf(psi0);
            const float f  = psi0 - nf;
            const int base = (int)nf + 12;
            const float fm = f + 1.0f, fp = f - 1.0f;
            const float wm = __expf(C_E * fm * fm) * xv0;
            const float w0 = __expf(C_E * f  * f ) * xv0;
            const float wp = __expf(C_E * fp * fp) * xv0;
            float* pb = mycol + (base << 8);
            float a0 = pb[0], a1 = pb[256], a2 = pb[512];
            a0 += wm; a1 += w0; a2 += wp;
            pb[0] = a0; pb[256] = a1; pb[512] = a2;
        }
        // ---- row 1: 3-neighbor binning + RMW (after row 0 in program order) ----
        {
            const float nf = rintf(psi1);
            const float f  = psi1 - nf;
            const int base = (int)nf + 12;
            const float fm = f + 1.0f, fp = f - 1.0f;
            const float wm = __expf(C_E * fm * fm) * xv1;
            const float w0 = __expf(C_E * f  * f ) * xv1;
            const float wp = __expf(C_E * fp * fp) * xv1;
            float* pb = mycol + (base << 8);
            float a0 = pb[0], a1 = pb[256], a2 = pb[512];
            a0 += wm; a1 += w0; a2 += wp;
            pb[0] = a0; pb[256] = a1; pb[512] = a2;
        }
    }

    __syncthreads();

    // Tail: reduce 16 col-phases per (r,z); fold wrap slots; atomicAdd to acc.
    for (int o = tid; o < NPART; o += 256) {
        const int r  = o >> 4;
        const int zz = o & 15;
        float s = 0.0f;
        #pragma unroll
        for (int c = 0; c < 16; ++c) {
            float v = red[r + 1][c * 16 + zz];   // slot r+1 holds bin r
            if (r == 0)  v += red[25][c * 16 + zz];  // bin 24 == 0
            if (r == 1)  v += red[26][c * 16 + zz];  // bin 25 == 1
            if (r == 23) v += red[0][c * 16 + zz];   // bin -1 == 23
            s += v;
        }
        atomicAdd(&g_acc[bf * NPART + o], s);    // device-scope, LLC-coherent
    }

    // am-I-last: per-thread drain, then one counter bump per block
    __threadfence();
    __syncthreads();
    __shared__ unsigned int s_last;
    if (tid == 0) s_last = (atomicAdd(&g_count, 1u) == NBLOCKS - 1) ? 1u : 0u;
    __syncthreads();
    if (s_last == 0) return;

    // ---- last block only: finalize all 1536 outputs, then reset state ----
    __threadfence();                             // acquire side
    #pragma unroll
    for (int k = 0; k < NOUT / 256; ++k) {
        const int o = tid + k * 256;
        const float s = __hip_atomic_load(&g_acc[o], __ATOMIC_RELAXED,
                                          __HIP_MEMORY_SCOPE_AGENT);
        out[o] = sqrtf(7.9788456080286535f * s);  // 2 * 1/(sigma*sqrt(2pi))
        __hip_atomic_store(&g_acc[o], 0.0f, __ATOMIC_RELAXED,
                           __HIP_MEMORY_SCOPE_AGENT);   // re-arm for next replay
    }
    if (tid == 0)
        __hip_atomic_store(&g_count, 0u, __ATOMIC_RELAXED,
                           __HIP_MEMORY_SCOPE_AGENT);   // re-arm counter
}

extern "C" void kernel_launch(void* const* d_in, const int* in_sizes, int n_in,
                              void* d_out, int out_size, void* d_ws, size_t ws_size,
                              hipStream_t stream)
{
    const float* x  = (const float*)d_in[0];
    const float* cr = (const float*)d_in[1];
    const float* ci = (const float*)d_in[2];
    float* out = (float*)d_out;

    grx_fused<<<dim3(NBLOCKS), dim3(256), 0, stream>>>(x, cr, ci, out);
}

// Round 9
// 73.877 us; speedup vs baseline: 2.4114x; 1.8364x over previous
//
#include <hip/hip_runtime.h>

#define NR 24
#define NBATCH 2
#define NFEAT 2
#define NX 256
#define NY 256
#define NZ 16
#define SLOTS 27          // bins -1..25 unwrapped (no mod-24 in hot loop)
#define NBLK_PER_BF 256   // 128 row-pairs x 2 col-halves
#define NPART (NR * NZ)   // 384 outputs per bf
#define NOUT (NBATCH * NFEAT * NPART)

// Round 9 = round-4 two-kernel skeleton (best: 74.4) + R8's interleaved-row
// hot loop (numerically verified in R8).
//
// Sync-primitive ledger (all measured, rounds 1-8): grid.sync ~70us,
// flag-spin handshake ~95us, grid-wide __threadfence ~60us, LDS atomic
// ~219cyc/op. Single-launch fusion is dead on MI355X; 2 launches optimal.
//
// Hot loop: both rows' atan2/exp chains computed before either LDS RMW ->
// 2 independent latency chains per iter (the RMW's ds_read latency no longer
// gates the next row's start), shared fabsf(dx)/sign logic.
// LDS transposed red[slot][tid]: bank = tid%32, conflict-free vs the
// data-dependent slot (2-way l/l+32 aliasing is free, m136).
__global__ __launch_bounds__(256) void grx_partial(
    const float* __restrict__ x,
    const float* __restrict__ com_real,
    const float* __restrict__ com_imag,
    float* __restrict__ ws)
{
    __shared__ float red[SLOTS][256];   // 27.6 KiB -> 4 blocks/CU resident

    const int tid  = threadIdx.x;
    const int z    = tid & 15;
    const int c0   = tid >> 4;
    const int half = blockIdx.x & 1;
    const int rp   = (blockIdx.x >> 1) & 127;
    const int bf   = blockIdx.x >> 8;          // 0..3

    // cooperative vectorized zero: 1728 float4, 7 b128 stores/thread
    float4* r4 = (float4*)&red[0][0];
    #pragma unroll
    for (int i = 0; i < 7; ++i) {
        const int idx = tid + i * 256;
        if (idx < (SLOTS * 256 / 4)) r4[idx] = make_float4(0.f, 0.f, 0.f, 0.f);
    }
    __syncthreads();

    const float comr = com_real[bf * NZ + z];
    const float comi = com_imag[bf * NZ + z];

    // atan poly coefficients pre-scaled by 12/pi (result directly in bin units)
    const float A4 = 0.0795845f;
    const float A3 = -0.3251843f;
    const float A2 = 0.6880875f;
    const float A1 = -1.2616510f;
    const float A0 = 3.8192070f;
    const float C_E = -3.4269908169872414f;    // -50*(pi/12)^2

    const int col0 = c0 + (half << 7);
    float* mycol = &red[0][tid];               // column owned by this thread

    const int row0   = rp * 2;
    const float dy0  = (float)row0 - comi;
    const float dy1  = dy0 + 1.0f;
    const float ady0 = fabsf(dy0);
    const float ady1 = fabsf(dy1);
    const float* xq0 = x + ((size_t)(bf * NX + row0) * (NY * NZ)) + (col0 * NZ + z);
    const float* xq1 = xq0 + NY * NZ;
    float dxv = (float)col0 - comr;            // shared by both rows; += 16/iter

    #pragma unroll
    for (int kk = 0; kk < 8; ++kk) {
        const float xv0 = xq0[kk * 256];       // 64 consecutive floats per wave
        const float xv1 = xq1[kk * 256];

        const float adx = fabsf(dxv);
        const bool  neg = (dxv < 0.0f);

        // ---- row 0: custom atan2 in bin units (|err| ~1e-5 rad equiv) ----
        const float mn0 = fminf(adx, ady0);
        const float mx0 = fmaxf(adx, ady0);
        const float t0  = mn0 * __builtin_amdgcn_rcpf(fmaxf(mx0, 1e-30f));
        const float q0  = t0 * t0;
        float p0 = fmaf(q0, A4, A3);
        p0 = fmaf(q0, p0, A2);
        p0 = fmaf(q0, p0, A1);
        p0 = fmaf(q0, p0, A0);
        float psi0 = t0 * p0;
        if (ady0 > adx) psi0 = 6.0f - psi0;
        if (neg)        psi0 = 12.0f - psi0;
        psi0 = copysignf(psi0, dy0);

        // ---- row 1: independent chain, shared adx/neg ----
        const float mn1 = fminf(adx, ady1);
        const float mx1 = fmaxf(adx, ady1);
        const float t1  = mn1 * __builtin_amdgcn_rcpf(fmaxf(mx1, 1e-30f));
        const float q1  = t1 * t1;
        float p1 = fmaf(q1, A4, A3);
        p1 = fmaf(q1, p1, A2);
        p1 = fmaf(q1, p1, A1);
        p1 = fmaf(q1, p1, A0);
        float psi1 = t1 * p1;
        if (ady1 > adx) psi1 = 6.0f - psi1;
        if (neg)        psi1 = 12.0f - psi1;
        psi1 = copysignf(psi1, dy1);

        dxv += 16.0f;

        // ---- row 0: 3-neighbor binning + RMW ----
        {
            const float nf = rintf(psi0);
            const float f  = psi0 - nf;
            const int base = (int)nf + 12;     // [0,24] -> slots base..base+2
            const float fm = f + 1.0f, fp = f - 1.0f;
            const float wm = __expf(C_E * fm * fm) * xv0;
            const float w0 = __expf(C_E * f  * f ) * xv0;
            const float wp = __expf(C_E * fp * fp) * xv0;
            float* pb = mycol + (base << 8);   // &red[base][tid], conflict-free
            float a0 = pb[0], a1 = pb[256], a2 = pb[512];
            a0 += wm; a1 += w0; a2 += wp;
            pb[0] = a0; pb[256] = a1; pb[512] = a2;
        }
        // ---- row 1: RMW after row 0 (DS pipe in-order per wave -> safe
        //      even when base0 == base1) ----
        {
            const float nf = rintf(psi1);
            const float f  = psi1 - nf;
            const int base = (int)nf + 12;
            const float fm = f + 1.0f, fp = f - 1.0f;
            const float wm = __expf(C_E * fm * fm) * xv1;
            const float w0 = __expf(C_E * f  * f ) * xv1;
            const float wp = __expf(C_E * fp * fp) * xv1;
            float* pb = mycol + (base << 8);
            float a0 = pb[0], a1 = pb[256], a2 = pb[512];
            a0 += wm; a1 += w0; a2 += wp;
            pb[0] = a0; pb[256] = a1; pb[512] = a2;
        }
    }

    __syncthreads();

    // Reduce over 16 col-phases per (r,z); fold wrap slots; transposed store.
    const int l = blockIdx.x & (NBLK_PER_BF - 1);
    for (int o = tid; o < NPART; o += 256) {
        const int r  = o >> 4;
        const int zz = o & 15;
        float s = 0.0f;
        #pragma unroll
        for (int c = 0; c < 16; ++c) {
            float v = red[r + 1][c * 16 + zz];   // slot r+1 holds bin r
            if (r == 0)  v += red[25][c * 16 + zz];  // bin 24 == 0
            if (r == 1)  v += red[26][c * 16 + zz];  // bin 25 == 1
            if (r == 23) v += red[0][c * 16 + zz];   // bin -1 == 23
            s += v;
        }
        ws[((size_t)(bf * NPART + o) * NBLK_PER_BF) + l] = s;
    }
}

// Stage 2: one block per output element; contiguous 256-float run, wave reduce.
__global__ __launch_bounds__(256) void grx_reduce(
    const float* __restrict__ ws, float* __restrict__ out)
{
    const int b   = blockIdx.x;          // 0..1535
    const int tid = threadIdx.x;
    float s = ws[(size_t)b * NBLK_PER_BF + tid];

    #pragma unroll
    for (int off = 32; off; off >>= 1) s += __shfl_down(s, off, 64);

    __shared__ float w4[4];
    if ((tid & 63) == 0) w4[tid >> 6] = s;
    __syncthreads();
    if (tid == 0) {
        // 2 * 1/(sigma*sqrt(2*pi))
        out[b] = sqrtf(7.9788456080286535f * (w4[0] + w4[1] + w4[2] + w4[3]));
    }
}

extern "C" void kernel_launch(void* const* d_in, const int* in_sizes, int n_in,
                              void* d_out, int out_size, void* d_ws, size_t ws_size,
                              hipStream_t stream)
{
    const float* x  = (const float*)d_in[0];
    const float* cr = (const float*)d_in[1];
    const float* ci = (const float*)d_in[2];
    float* out = (float*)d_out;
    float* ws  = (float*)d_ws;

    grx_partial<<<dim3(NBATCH * NFEAT * NBLK_PER_BF), dim3(256), 0, stream>>>(x, cr, ci, ws);
    grx_reduce<<<dim3(NBATCH * NFEAT * NPART), dim3(256), 0, stream>>>(ws, out);
}

// Round 10
// 73.651 us; speedup vs baseline: 2.4188x; 1.0031x over previous
//
#include <hip/hip_runtime.h>

#define NR 24
#define NBATCH 2
#define NFEAT 2
#define NX 256
#define NY 256
#define NZ 16
#define SLOTS 27          // bins -1..25 unwrapped (no mod-24 in hot loop)
#define NBLK_PER_BF 256   // 128 row-pairs x 2 col-halves
#define NPART (NR * NZ)   // 384 outputs per bf
#define NOUT (NBATCH * NFEAT * NPART)

// Round 10 = round-9 stage 1 (best: 73.9) + lighter stage 2.
//
// Session ledger (rounds 0-9, all measured): fill 42.7us (harness, fixed) +
// ~16us 2-node graph overhead + partial ~12 + reduce ~3. Fusion topologies
// all dead on MI355X: grid.sync ~70us, flag-spin ~95us, grid-wide
// __threadfence ~60us, LDS atomics ~219cyc/op. 2-launch structure optimal.
//
// Stage 1: per (bf,row-pair,col-half) block; thread = (col-phase, z).
// 3-tap circular binning in "bin units" (theta*12/pi); LDS transposed
// red[slot][tid] -> bank = tid%32, conflict-free vs data-dependent slot
// (2-way l/l+32 aliasing free, m136). Rows interleaved: 2 independent
// atan2/exp chains per iter before either LDS RMW (R9: -0.5us).
__global__ __launch_bounds__(256) void grx_partial(
    const float* __restrict__ x,
    const float* __restrict__ com_real,
    const float* __restrict__ com_imag,
    float* __restrict__ ws)
{
    __shared__ float red[SLOTS][256];   // 27.6 KiB -> 4 blocks/CU resident

    const int tid  = threadIdx.x;
    const int z    = tid & 15;
    const int c0   = tid >> 4;
    const int half = blockIdx.x & 1;
    const int rp   = (blockIdx.x >> 1) & 127;
    const int bf   = blockIdx.x >> 8;          // 0..3

    // cooperative vectorized zero: 1728 float4, 7 b128 stores/thread
    float4* r4 = (float4*)&red[0][0];
    #pragma unroll
    for (int i = 0; i < 7; ++i) {
        const int idx = tid + i * 256;
        if (idx < (SLOTS * 256 / 4)) r4[idx] = make_float4(0.f, 0.f, 0.f, 0.f);
    }
    __syncthreads();

    const float comr = com_real[bf * NZ + z];
    const float comi = com_imag[bf * NZ + z];

    // atan poly coefficients pre-scaled by 12/pi (result directly in bin units)
    const float A4 = 0.0795845f;
    const float A3 = -0.3251843f;
    const float A2 = 0.6880875f;
    const float A1 = -1.2616510f;
    const float A0 = 3.8192070f;
    const float C_E = -3.4269908169872414f;    // -50*(pi/12)^2

    const int col0 = c0 + (half << 7);
    float* mycol = &red[0][tid];               // column owned by this thread

    const int row0   = rp * 2;
    const float dy0  = (float)row0 - comi;
    const float dy1  = dy0 + 1.0f;
    const float ady0 = fabsf(dy0);
    const float ady1 = fabsf(dy1);
    const float* xq0 = x + ((size_t)(bf * NX + row0) * (NY * NZ)) + (col0 * NZ + z);
    const float* xq1 = xq0 + NY * NZ;
    float dxv = (float)col0 - comr;            // shared by both rows; += 16/iter

    #pragma unroll
    for (int kk = 0; kk < 8; ++kk) {
        const float xv0 = xq0[kk * 256];       // 64 consecutive floats per wave
        const float xv1 = xq1[kk * 256];

        const float adx = fabsf(dxv);
        const bool  neg = (dxv < 0.0f);

        // ---- row 0: custom atan2 in bin units (|err| ~1e-5 rad equiv) ----
        const float mn0 = fminf(adx, ady0);
        const float mx0 = fmaxf(adx, ady0);
        const float t0  = mn0 * __builtin_amdgcn_rcpf(fmaxf(mx0, 1e-30f));
        const float q0  = t0 * t0;
        float p0 = fmaf(q0, A4, A3);
        p0 = fmaf(q0, p0, A2);
        p0 = fmaf(q0, p0, A1);
        p0 = fmaf(q0, p0, A0);
        float psi0 = t0 * p0;
        if (ady0 > adx) psi0 = 6.0f - psi0;
        if (neg)        psi0 = 12.0f - psi0;
        psi0 = copysignf(psi0, dy0);

        // ---- row 1: independent chain, shared adx/neg ----
        const float mn1 = fminf(adx, ady1);
        const float mx1 = fmaxf(adx, ady1);
        const float t1  = mn1 * __builtin_amdgcn_rcpf(fmaxf(mx1, 1e-30f));
        const float q1  = t1 * t1;
        float p1 = fmaf(q1, A4, A3);
        p1 = fmaf(q1, p1, A2);
        p1 = fmaf(q1, p1, A1);
        p1 = fmaf(q1, p1, A0);
        float psi1 = t1 * p1;
        if (ady1 > adx) psi1 = 6.0f - psi1;
        if (neg)        psi1 = 12.0f - psi1;
        psi1 = copysignf(psi1, dy1);

        dxv += 16.0f;

        // ---- row 0: 3-neighbor binning + RMW ----
        {
            const float nf = rintf(psi0);
            const float f  = psi0 - nf;
            const int base = (int)nf + 12;     // [0,24] -> slots base..base+2
            const float fm = f + 1.0f, fp = f - 1.0f;
            const float wm = __expf(C_E * fm * fm) * xv0;
            const float w0 = __expf(C_E * f  * f ) * xv0;
            const float wp = __expf(C_E * fp * fp) * xv0;
            float* pb = mycol + (base << 8);   // &red[base][tid], conflict-free
            float a0 = pb[0], a1 = pb[256], a2 = pb[512];
            a0 += wm; a1 += w0; a2 += wp;
            pb[0] = a0; pb[256] = a1; pb[512] = a2;
        }
        // ---- row 1: RMW after row 0 (DS pipe in-order per wave -> safe
        //      even when base0 == base1) ----
        {
            const float nf = rintf(psi1);
            const float f  = psi1 - nf;
            const int base = (int)nf + 12;
            const float fm = f + 1.0f, fp = f - 1.0f;
            const float wm = __expf(C_E * fm * fm) * xv1;
            const float w0 = __expf(C_E * f  * f ) * xv1;
            const float wp = __expf(C_E * fp * fp) * xv1;
            float* pb = mycol + (base << 8);
            float a0 = pb[0], a1 = pb[256], a2 = pb[512];
            a0 += wm; a1 += w0; a2 += wp;
            pb[0] = a0; pb[256] = a1; pb[512] = a2;
        }
    }

    __syncthreads();

    // Tail: reduce 16 col-phases per (r,z); fold wrap slots; transposed store.
    // 384 outputs / 256 threads: one full pass + a half pass (threads 0-127),
    // no wasted full-wave second sweep for threads 128-255.
    const int l = blockIdx.x & (NBLK_PER_BF - 1);
    {
        const int o  = tid;                    // 0..255
        const int r  = o >> 4;
        const int zz = o & 15;
        float s = 0.0f;
        #pragma unroll
        for (int c = 0; c < 16; ++c) {
            float v = red[r + 1][c * 16 + zz];
            if (r == 0) v += red[25][c * 16 + zz];   // bin 24 == 0
            if (r == 1) v += red[26][c * 16 + zz];   // bin 25 == 1
            s += v;
        }
        ws[((size_t)(bf * NPART + o) * NBLK_PER_BF) + l] = s;
    }
    if (tid < 128) {
        const int o  = 256 + tid;              // 256..383
        const int r  = o >> 4;                 // 16..23
        const int zz = o & 15;
        float s = 0.0f;
        #pragma unroll
        for (int c = 0; c < 16; ++c) {
            float v = red[r + 1][c * 16 + zz];
            if (r == 23) v += red[0][c * 16 + zz];   // bin -1 == 23
            s += v;
        }
        ws[((size_t)(bf * NPART + o) * NBLK_PER_BF) + l] = s;
    }
}

// Stage 2: 384 blocks, one wave per output; float4 per lane covers the whole
// 256-float run; pure shuffle reduce -- no LDS, no barrier.
__global__ __launch_bounds__(256) void grx_reduce(
    const float* __restrict__ ws, float* __restrict__ out)
{
    const int o    = blockIdx.x * 4 + (threadIdx.x >> 6);  // 0..1535
    const int lane = threadIdx.x & 63;
    const float4 v = ((const float4*)(ws + (size_t)o * NBLK_PER_BF))[lane];
    float s = (v.x + v.y) + (v.z + v.w);

    #pragma unroll
    for (int off = 32; off; off >>= 1) s += __shfl_down(s, off, 64);

    if (lane == 0) {
        // 2 * 1/(sigma*sqrt(2*pi))
        out[o] = sqrtf(7.9788456080286535f * s);
    }
}

extern "C" void kernel_launch(void* const* d_in, const int* in_sizes, int n_in,
                              void* d_out, int out_size, void* d_ws, size_t ws_size,
                              hipStream_t stream)
{
    const float* x  = (const float*)d_in[0];
    const float* cr = (const float*)d_in[1];
    const float* ci = (const float*)d_in[2];
    float* out = (float*)d_out;
    float* ws  = (float*)d_ws;

    grx_partial<<<dim3(NBATCH * NFEAT * NBLK_PER_BF), dim3(256), 0, stream>>>(x, cr, ci, ws);
    grx_reduce<<<dim3(NOUT / 4), dim3(256), 0, stream>>>(ws, out);
}